// Round 18
// baseline (235.528 us; speedup 1.0000x reference)
//
#include <hip/hip_runtime.h>

typedef __attribute__((ext_vector_type(4))) float f32x4;
typedef __attribute__((ext_vector_type(2))) unsigned int u32x2;
typedef _Float16 f16x8 __attribute__((ext_vector_type(8)));
typedef _Float16 h2    __attribute__((ext_vector_type(2)));

#define TTOK 10000
#define SBAR() __builtin_amdgcn_sched_barrier(0)

__device__ __forceinline__ h2 pkh(float lo, float hi){
  auto t = __builtin_amdgcn_cvt_pkrtz(lo, hi);   // __fp16 x2 -> bitcast to h2
  union{ decltype(t) a; h2 b; } c; c.a = t; return c.b;
}
__device__ __forceinline__ unsigned h2u(h2 v){ union{h2 h; unsigned u;} c; c.h=v; return c.u; }

__device__ __forceinline__ unsigned short f2h(float f){
  _Float16 h = (_Float16)f;                 // RNE
  union{_Float16 h; unsigned short u;} c; c.h = h; return c.u;
}

// ---------------- prep: fragment-linear f16 weights, hb+t*tw seeds, c ----------------
// wb[((jj*4+kc)*64 + l)*8 + i] = W[jj*16+q][kc*32+g*8+i], l=g*16+q: a wave's
// 16B/lane fragment read is 64 lanes x contiguous = 1024B (conflict-free),
// address = base + immediate (round 13, verified).
__global__ void cnf_prep(const float* __restrict__ h, const float* __restrict__ Wx,
                         const float* __restrict__ wxt, const float* __restrict__ bx,
                         const float* __restrict__ Wh, const float* __restrict__ wht,
                         const float* __restrict__ bh, const float* __restrict__ W2,
                         float* __restrict__ hbt, float* __restrict__ cv,
                         unsigned short* __restrict__ wxb, unsigned short* __restrict__ w2b)
{
  const int b = blockIdx.x, t = threadIdx.x;
  if (b < 16) {
    const int jj = b & 7;
    const float* W = (b < 8) ? Wx : W2;
    unsigned short* dst = (b < 8) ? wxb : w2b;
    const int kc = t>>6, l = t&63, q = l&15, g = l>>4;
    #pragma unroll
    for (int i=0;i<8;++i)
      dst[((jj*4+kc)*64 + l)*8 + i] = f2h(W[(jj*16+q)*128 + kc*32 + g*8 + i]);
  } else if (b < 18) {
    for (int i=0;i<4;++i){
      int idx = i*256 + t;
      int sb = (b-16)*8 + (idx>>7);
      int j  = idx & 127;
      float a = 0.f;
      for (int e2=0;e2<128;++e2) a += h[sb*128+e2]*Wh[j*128+e2];
      float base = a + bh[j] + bx[j];
      float tw   = wxt[j] + wht[j];
      for (int ti=0; ti<5; ++ti)
        hbt[(ti*16+sb)*128 + j] = base + 0.25f*(float)ti*tw;   // t in {0,.25,.5,.75,1}
    }
  } else {
    if (t < 128){
      float a = 0.f;
      for (int i=0;i<128;++i) a += W2[i*128+t]*Wx[t*128+i];
      cv[t] = a;
    }
  }
}

// ---------------- fused CNF main kernel ----------------
// Round-18: barrier-free eval loop. f16-packed state shrank per-wave demand
// enough that ONE wave owns a full 16-row x 128-dim tile (impossible in
// fp32 — that forced rounds 10-17's h-split and its 4 syncthreads/eval).
// Wave-private 4KB transpose buffer (z^T then sp^T, wave-local lgkmcnt
// ordering); weights read-only after stage. ZERO intra-loop barriers.
// LDS addresses precomputed (static-index arrays -> registers). LDS 64KB
// weights + 4x4KB bufs = 80KB -> 2 blocks/CU.
__global__ __launch_bounds__(256, 2) void cnf_main(
    const float* __restrict__ emb, const float* __restrict__ lp0,
    const float* __restrict__ b2g, const float* __restrict__ hbt,
    const float* __restrict__ cg,  const unsigned short* __restrict__ wxb,
    const unsigned short* __restrict__ w2b, float* __restrict__ out)
{
  __shared__ __align__(16) unsigned short sWx[16384];
  __shared__ __align__(16) unsigned short sW2[16384];
  __shared__ __align__(16) unsigned short sT[4][2048];   // per-WAVE z^T/sp^T buffer (4KB)

  const int tid = threadIdx.x;
  const int rowbase = blockIdx.x*64;

  // stage weights into LDS: plain linear copy (layout already fragment-linear)
  for (int it=0; it<8; ++it){
    int L = it*4096 + tid*16;
    *(int4*)((char*)sWx + L) = *(const int4*)((const char*)wxb + L);
    *(int4*)((char*)sW2 + L) = *(const int4*)((const char*)w2b + L);
  }
  __syncthreads();   // the ONLY block-wide barrier

  const int w = tid>>6, l = tid&63, q = l&15, g = l>>4;
  char* tB = (char*)&sT[w][0];
  const char* wxBase = (const char*)sWx + l*16;   // + (j*4+kc)*1024 imm, j 0..7
  const char* w2Base = (const char*)sW2 + l*16;
  const int cwB = q*16 + 8*(g&1) + 256*(g>>1);
  const int crB = g*256 + q*16;

  // loop-invariant swizzled LDS addresses (static indices -> registers)
  int wadr[8], radr[4];
  #pragma unroll
  for (int j=0; j<8; ++j){ int W = j*512 + cwB; W ^= ((W>>8)&7)<<4; wadr[j] = W; }
  #pragma unroll
  for (int kc=0; kc<4; ++kc){ int R = kc*1024 + crB; R ^= ((R>>8)&7)<<4; radr[kc] = R; }

  const int row = rowbase + w*16 + q;
  const int sb  = row/TTOK, tt = row - sb*TTOK;

  h2 zbp[8][2];        // z state, packed f16 (16 VGPRs), elem e = 16j+4g+r
  h2 ksp[8][2];        // RK4 running sum, packed f16 (16 VGPRs)
  f32x4 wk[8];         // f32 accumulators (acc file)
  float dlt = 0.f;

  #pragma unroll
  for (int j=0; j<8; ++j){
    f32x4 e4 = *(const f32x4*)(emb + tt*128 + 16*j + 4*g);
    zbp[j][0] = pkh(e4[0], e4[1]);
    zbp[j][1] = pkh(e4[2], e4[3]);
    wk[j] = (f32x4){0.f,0.f,0.f,0.f};
    ksp[j][0] = (h2){0,0}; ksp[j][1] = (h2){0,0};
  }

  #pragma unroll 1
  for (int se=0; se<8; ++se){
    const int   s    = se>>2, e = se&3;
    const float coef = (e==0)?0.f:((e==3)?0.5f:0.25f); // z_eval = z_base + coef*k_prev
    const float we   = (e==1||e==2)?2.f:1.f;
    const int   ti   = 2*s + ((e==0)?0:((e<3)?1:2));
    const _Float16 ch = (_Float16)coef;
    const h2 coef2 = {ch, ch};
    const _Float16 wh_ = (_Float16)we;
    const h2 we2 = {wh_, wh_};
    const h2 c12 = {(_Float16)(1.f/12.f), (_Float16)(1.f/12.f)};

    // ---- phase 1: prefetch hb seeds; pack z_eval -> z^T (wave-private)
    f32x4 hb[8];
    {
      const float* p = hbt + (ti*16 + sb)*128 + 4*g;
      #pragma unroll
      for (int j=0; j<8; ++j) hb[j] = *(const f32x4*)(p + 16*j);
    }
    #pragma unroll
    for (int j=0; j<8; ++j){
      u32x2 wv;
      if (e==0){
        wv[0] = h2u(zbp[j][0]); wv[1] = h2u(zbp[j][1]);
      } else {
        h2 a0 = pkh(wk[j][0], wk[j][1]);
        h2 a1 = pkh(wk[j][2], wk[j][3]);
        h2 z0 = coef2*a0 + zbp[j][0];
        h2 z1 = coef2*a1 + zbp[j][1];
        wv[0] = h2u(z0); wv[1] = h2u(z1);
      }
      *(u32x2*)(tB + wadr[j]) = wv;
    }
    SBAR();

    // ---- phase 2: matmul1: pre = Wx . zT (full K, seed = prefetched hb)
    #pragma unroll
    for (int j=0; j<8; ++j) wk[j] = hb[j];
    #pragma unroll
    for (int kc=0; kc<4; ++kc){
      f16x8 zf = *(const f16x8*)(tB + radr[kc]);
      #pragma unroll
      for (int j=0; j<8; ++j){
        f16x8 af = *(const f16x8*)(wxBase + (j*4+kc)*1024);
        wk[j] = __builtin_amdgcn_mfma_f32_16x16x32_f16(af, zf, wk[j], 0,0,0);
      }
      SBAR();
    }

    // ---- phase 3: prefetch b2; softplus -> sp^T (overwrites z^T), sigmoid*c -> div
    f32x4 b2pf[8];
    {
      const float* p = b2g + 4*g;
      #pragma unroll
      for (int j=0; j<8; ++j) b2pf[j] = *(const f32x4*)(p + 16*j);
    }
    float dv = 0.f;
    #pragma unroll
    for (int j=0; j<8; ++j){
      f32x4 cc = *(const f32x4*)(cg + 16*j + 4*g);
      float sp[4];
      #pragma unroll
      for (int r=0;r<4;++r){
        float x  = wk[j][r];
        float ax = __builtin_fabsf(x);
        float ea = __expf(-ax);
        float opa = 1.0f + ea;
        float rc = __builtin_amdgcn_rcpf(opa);
        float lg = __logf(opa);
        sp[r] = fmaxf(x,0.f) + lg;                 // softplus
        float sg = (x >= 0.f) ? rc : ea*rc;        // sigmoid
        dv += sg*cc[r];
      }
      u32x2 wv = { h2u(pkh(sp[0],sp[1])), h2u(pkh(sp[2],sp[3])) };
      *(u32x2*)(tB + wadr[j]) = wv;
    }
    dlt += we*dv;
    SBAR();

    // ---- phase 4: matmul2: dz = W2 . spT (seed = prefetched b2)
    #pragma unroll
    for (int j=0; j<8; ++j) wk[j] = b2pf[j];
    #pragma unroll
    for (int kc=0; kc<4; ++kc){
      f16x8 sf = *(const f16x8*)(tB + radr[kc]);
      #pragma unroll
      for (int j=0; j<8; ++j){
        f16x8 af = *(const f16x8*)(w2Base + (j*4+kc)*1024);
        wk[j] = __builtin_amdgcn_mfma_f32_16x16x32_f16(af, sf, wk[j], 0,0,0);
      }
      SBAR();
    }

    // ---- phase 5: RK4 accumulate (wk = k_e), packed f16
    if (e==0){
      #pragma unroll
      for (int j=0;j<8;++j){
        ksp[j][0] = pkh(wk[j][0], wk[j][1]);
        ksp[j][1] = pkh(wk[j][2], wk[j][3]);
      }
    } else if (e<3){
      #pragma unroll
      for (int j=0;j<8;++j){
        ksp[j][0] = we2*pkh(wk[j][0], wk[j][1]) + ksp[j][0];
        ksp[j][1] = we2*pkh(wk[j][2], wk[j][3]) + ksp[j][1];
      }
    } else {
      #pragma unroll
      for (int j=0;j<8;++j){
        h2 t0 = ksp[j][0] + pkh(wk[j][0], wk[j][1]);
        h2 t1 = ksp[j][1] + pkh(wk[j][2], wk[j][3]);
        zbp[j][0] = c12*t0 + zbp[j][0];
        zbp[j][1] = c12*t1 + zbp[j][1];
      }
    }
    SBAR();
  }

  // ---- epilogue: reduce div partials over the 4 g-lanes, write log_pz1
  {
    float d = dlt*(1.f/12.f);
    d += __shfl_xor(d, 16, 64);
    d += __shfl_xor(d, 32, 64);
    if (g==0) out[row] = lp0[row] - d;
  }
}

extern "C" void kernel_launch(void* const* d_in, const int* in_sizes, int n_in,
                              void* d_out, int out_size, void* d_ws, size_t ws_size,
                              hipStream_t stream) {
  const float* h    = (const float*)d_in[0];
  const float* emb  = (const float*)d_in[1];
  const float* lp0  = (const float*)d_in[2];
  const float* Wx   = (const float*)d_in[3];
  const float* wxt  = (const float*)d_in[4];
  const float* bx   = (const float*)d_in[5];
  const float* Wh   = (const float*)d_in[6];
  const float* wht  = (const float*)d_in[7];
  const float* bh   = (const float*)d_in[8];
  const float* W2   = (const float*)d_in[9];
  const float* b2   = (const float*)d_in[10];
  float* out = (float*)d_out;

  char* ws = (char*)d_ws;
  float* hbt          = (float*)ws;            // 5*16*128 f32 = 40960 B
  float* cv           = (float*)(ws + 40960);  // 128 f32     = 512 B
  unsigned short* wxb = (unsigned short*)(ws + 41472); // 16384 f16 = 32768 B
  unsigned short* w2b = (unsigned short*)(ws + 74240); // 16384 f16 = 32768 B

  cnf_prep<<<19, 256, 0, stream>>>(h, Wx, wxt, bx, Wh, wht, bh, W2, hbt, cv, wxb, w2b);
  cnf_main<<<2500, 256, 0, stream>>>(emb, lp0, b2, hbt, cv, wxb, w2b, out);
}